// Round 19
// baseline (578.635 us; speedup 1.0000x reference)
//
#include <hip/hip_runtime.h>
#include <hip/hip_bf16.h>
#include <stdint.h>

#define B_ 16
#define T_ 30
#define H_ 64
#define W_ 44
#define HW_ (H_*W_)            // 2816
#define THW_ (T_*HW_)          // 84480

// padded transposed layout: xt[b][half][t:30][hp:66][wp:46][32 ic] bf16
#define HP_ 66
#define WP_ 46
#define PPLANE_ (HP_*WP_)      // 3036
#define PPOS_ (T_*PPLANE_)     // 91080 pos per (b,half)

// conv tiling: 256 thr (4 waves), out tile 2t x 6h x 16w = 192 pos, 64 oc
// wave: tzw = wid&1 (t), hw = (wid>>1)*3 (3 h rows); acc[4][3]
#define NS3 576                // 4z x 8y x 18x staged rows (64 B each per K-half)

// LDS 16B-chunk swizzle (validated R3/R10: SQ_LDS_BANK_CONFLICT = 0)
#define SWZ(v) (((v) >> 1) & 3)

typedef __bf16 bf16x8 __attribute__((ext_vector_type(8)));
typedef float f32x4 __attribute__((ext_vector_type(4)));

static __device__ __forceinline__ short f2bf(float f) {
    __hip_bfloat16 h = __float2bfloat16(f);
    union { __hip_bfloat16 b; short s; } u; u.b = h; return u.s;
}

static __device__ __forceinline__ void gload_lds16(const short* g, short* l) {
    __builtin_amdgcn_global_load_lds((const __attribute__((address_space(1))) void*)g,
                                     (__attribute__((address_space(3))) void*)l, 16, 0, 0);
}

// ---------------- kernel 0: transpose + fused GAP ----------------
__global__ __launch_bounds__(256) void transpose_kernel(const float* __restrict__ x,
                                                        short* __restrict__ xt,
                                                        float* __restrict__ gap) {
    __shared__ short lb[64*52];
    __shared__ float gsum[64];
    int blk = blockIdx.x;
    int b = blk / (T_*HP_);
    int r = blk - b*(T_*HP_);
    int t = r / HP_;
    int hp = r - t*HP_;
    int tid = threadIdx.x;
    bool interior = (hp >= 1) && (hp <= H_);
    float rsum = 0.f;
    {
        int ic = tid >> 2, g = tid & 3;
        if (interior) {
            int h = hp - 1;
            const float4* row = (const float4*)(x + ((size_t)(b*64 + ic)*T_ + t)*HW_ + h*W_);
            #pragma unroll
            for (int q = g; q < 11; q += 4) {
                float4 v = row[q];
                short4 s4;
                s4.x = f2bf(v.x); s4.y = f2bf(v.y); s4.z = f2bf(v.z); s4.w = f2bf(v.w);
                *(short4*)&lb[ic*52 + q*4] = s4;
                rsum += (v.x + v.y) + (v.z + v.w);
            }
        }
        rsum += __shfl_xor(rsum, 1);
        rsum += __shfl_xor(rsum, 2);
        if ((tid & 3) == 0) gsum[ic] = rsum;
    }
    __syncthreads();
    if (interior && tid < 64)
        atomicAdd(&gap[b*64 + tid], gsum[tid] * (1.0f / THW_));
    for (int e = tid; e < WP_*16; e += 256) {
        int wp = e >> 4, i4 = (e & 15) * 4;
        short4 s4 = make_short4(0,0,0,0);
        if (interior && wp >= 1 && wp <= W_) {
            int w = wp - 1;
            s4.x = lb[(i4+0)*52 + w];
            s4.y = lb[(i4+1)*52 + w];
            s4.z = lb[(i4+2)*52 + w];
            s4.w = lb[(i4+3)*52 + w];
        }
        size_t pos = (size_t)t*PPLANE_ + hp*WP_ + wp;
        short* dst = xt + ((size_t)(b*2 + (i4 >> 5))*PPOS_ + pos)*32 + (i4 & 31);
        *(short4*)dst = s4;
    }
}

// ---------------- kernel 2: reduce FC + fc1 + sigmoid ----------------
__global__ __launch_bounds__(256) void fc_kernel(const float* __restrict__ gap,
        const float* __restrict__ w_reduce, const float* __restrict__ b_reduce,
        const float* __restrict__ w_fc1, const float* __restrict__ b_fc1,
        float* __restrict__ h_out) {
    __shared__ float gl[256];
    int t = threadIdx.x;
    {
        int b = t >> 4, j = t & 15;
        float a = b_reduce[j];
        #pragma unroll
        for (int c = 0; c < 64; ++c) a += gap[b*64 + c] * w_reduce[j*64 + c];
        gl[b*16 + j] = a;
    }
    __syncthreads();
    for (int idx = t; idx < 2048; idx += 256) {
        int b = idx >> 7, j = idx & 127;
        float v = b_fc1[j];
        #pragma unroll
        for (int i = 0; i < 16; ++i) v += gl[b*16 + i] * w_fc1[j*16 + i];
        h_out[idx] = 1.0f / (1.0f + expf(-v));
    }
}

// ---------------- kernel 3: dynamic weights bf16 (+ zero block) ----------------
__global__ __launch_bounds__(256) void wdyn_kernel(const float* __restrict__ w_fc2,
        const float* __restrict__ h, short* __restrict__ wdyn, short* __restrict__ zblk) {
    if (blockIdx.x == 0 && threadIdx.x < 128) zblk[threadIdx.x] = 0;
    int b = blockIdx.x / 27, tap = blockIdx.x % 27;
    short* dst = wdyn + ((size_t)b*27 + tap) * 4096;
    for (int e = threadIdx.x; e < 4096; e += 256) {
        int oc = e >> 6, ic = e & 63;
        float wv = w_fc2[(oc*64 + ic)*27 + tap];
        float hv = h[b*128 + 2*oc + (ic >> 5)];
        dst[e] = f2bf(wv * hv);
    }
}

#define RAWBAR() do {                                                  \
    asm volatile("s_waitcnt lgkmcnt(0)" ::: "memory");                 \
    __builtin_amdgcn_s_barrier();                                      \
} while (0)

#define MF4(J, BV) do {                                                \
    acc[0][J] = __builtin_amdgcn_mfma_f32_16x16x32_bf16(a0, BV, acc[0][J], 0, 0, 0); \
    acc[1][J] = __builtin_amdgcn_mfma_f32_16x16x32_bf16(a1, BV, acc[1][J], 0, 0, 0); \
    acc[2][J] = __builtin_amdgcn_mfma_f32_16x16x32_bf16(a2, BV, acc[2][J], 0, 0, 0); \
    acc[3][J] = __builtin_amdgcn_mfma_f32_16x16x32_bf16(a3, BV, acc[3][J], 0, 0, 0); \
} while (0)

// B-rows (3) for tap-half gn into named regs (from stable xs)
#define BREADN(gn, N0, N1, N2) do {                                    \
    int _tap = (gn) - (((gn) >= 27) ? 27 : 0);                         \
    int _kd = _tap/9, _rm = _tap-9*_kd, _kh = _rm/3, _kw = _rm-3*_kh;  \
    int _sb = (tzw + _kd)*144 + (hw + _kh)*18 + _kw + ln;              \
    N0 = *(const bf16x8*)&xs[(_sb    )*32 + ((kg ^ SWZ(_sb    ))*8)];  \
    N1 = *(const bf16x8*)&xs[(_sb+18)*32 + ((kg ^ SWZ(_sb+18))*8)];   \
    N2 = *(const bf16x8*)&xs[(_sb+36)*32 + ((kg ^ SWZ(_sb+36))*8)];   \
} while (0)

// A-frags for tap-half gn+? from bank bk into na0..na3
#define AREADN(bk) do {                                                \
    const short* _wq = &wb[0][0] + ((bk) << 11);                       \
    int _cw = (kg ^ SWZ(ln)) * 8;                                      \
    na0 = *(const bf16x8*)&_wq[(ln     )*32 + _cw];                    \
    na1 = *(const bf16x8*)&_wq[(ln + 16)*32 + _cw];                    \
    na2 = *(const bf16x8*)&_wq[(ln + 32)*32 + _cw];                    \
    na3 = *(const bf16x8*)&_wq[(ln + 48)*32 + _cw];                    \
} while (0)

// ---------------- kernel 4: implicit-GEMM dynamic conv3d ----------------
// Fully operand-prefetched round: weights published TWO rounds ahead (2 banks)
// so round g prefetches AREAD W(g+1) AND BREAD B(g+1) during g's MFMAs; after
// the entry barrier the MFMA burst has zero LDS-read dependency. Bank hazard:
// bank[g&1] (overwritten in round g with W(g+2)) was last read in round g-1,
// separated by round g's entry barrier (lgkmcnt(0) per wave). vmcnt never
// drained in-loop; wr prefetched 3 rounds ahead.
__global__ __launch_bounds__(256, 3) void conv_kernel(const short* __restrict__ xt,
        const short* __restrict__ wdyn, const short* __restrict__ zblk,
        float* __restrict__ out) {
    __shared__ short xs[NS3*32];     // 36,864 B
    __shared__ short wb[2][2048];    //  8,192 B (2 tap banks)

    // XCD swizzle: 7920 blocks = 8 XCDs x 990 contiguous (7920 % 8 == 0)
    int bid = (blockIdx.x & 7) * 990 + (blockIdx.x >> 3);
    int b = bid / 495; int r = bid - b*495;
    int tzt = r / 33; r -= tzt*33;
    int tyt = r / 3;  int txt = r - tyt*3;
    int t0 = tzt*2, h0 = tyt*6, w0 = txt*16;

    int tid = threadIdx.x, wid = tid >> 6, lane = tid & 63;
    int ln = lane & 15, kg = lane >> 4;
    int l4 = lane >> 2, c = lane & 3;
    int tzw = wid & 1, hw = (wid >> 1) * 3;
    int woc = tid >> 2, wseg = tid & 3;          // weight staging role

    const short* wdb   = wdyn + (size_t)b * 27 * 4096;
    const short* wbase = wdb + woc*64 + wseg*8;
    short* wdst = &wb[0][0] + woc*32 + ((wseg ^ SWZ(woc)) * 8);

    f32x4 acc[4][3];
    #pragma unroll
    for (int mt = 0; mt < 4; ++mt)
        #pragma unroll
        for (int j = 0; j < 3; ++j) acc[mt][j] = f32x4{0.f, 0.f, 0.f, 0.f};

    auto wload = [&](int gn) {                   // weights for tap-half gn
        int tap = gn - ((gn >= 27) ? 27 : 0);
        int nh  = (gn >= 27) ? 32 : 0;
        return *(const uint4*)(wbase + tap*4096 + nh);
    };
    auto stage_x = [&](int half) {               // 36 gload_lds over 4 waves
        const short* xbh = xt + (size_t)(b*2 + half) * PPOS_ * 32;
        #pragma unroll
        for (int ii = 0; ii < 9; ++ii) {
            int inst = ii*4 + wid;
            int s = inst*16 + l4;
            int z = s / 144; int rr = s - z*144;
            int y = rr / 18; int xx = rr - y*18;
            int t = t0 + z - 1;
            int hp = h0 + y;
            int seg = (c ^ SWZ(s)) * 8;
            const short* src = ((unsigned)t < (unsigned)T_ && hp < HP_)
                ? xbh + ((size_t)t*PPLANE_ + hp*WP_ + (w0+xx))*32 + seg
                : zblk + seg;
            gload_lds16(src, xs + inst*512);
        }
    };

    // prologue: xs half 0; bank0=W(0), bank1=W(1); wr=W(2); a=W(0), b=B(0)
    stage_x(0);
    uint4 wr = wload(0);
    asm volatile("s_waitcnt vmcnt(0)" ::: "memory");   // xs(0) + W(0)
    *(uint4*)wdst = wr;
    wr = wload(1);
    asm volatile("s_waitcnt vmcnt(0)" ::: "memory");   // W(1)
    *(uint4*)(wdst + 2048) = wr;
    wr = wload(2);
    RAWBAR();                                          // xs + both banks visible
    bf16x8 a0, a1, a2, a3, na0, na1, na2, na3;
    bf16x8 b0, b1, b2, n0, n1, n2;
    AREADN(0); a0 = na0; a1 = na1; a2 = na2; a3 = na3;
    BREADN(0, b0, b1, b2);

    #pragma unroll 1
    for (int g = 0; g < 54; ++g) {
        RAWBAR();                                // my prev reads done; all
                                                 // publishes from g-1 visible
        if (g <= 51) {
            *(uint4*)(wdst + ((g & 1) << 11)) = wr;    // publish W(g+2)
            if (g <= 50) wr = wload(g + 3);
        }
        if (g <= 52) {
            AREADN((g + 1) & 1);                 // prefetch A of round g+1
            if (g != 26) BREADN(g + 1, n0, n1, n2);
        }
        __builtin_amdgcn_s_setprio(1);           // operands already in regs
        MF4(0, b0); MF4(1, b1); MF4(2, b2);
        __builtin_amdgcn_s_setprio(0);
        if (g == 26) {                           // half transition
            RAWBAR();                            // all xs(0) reads consumed
            stage_x(1);
            asm volatile("s_waitcnt vmcnt(0)" ::: "memory");
            __builtin_amdgcn_s_barrier();        // xs(1) landed everywhere
            BREADN(27, n0, n1, n2);
        }
        a0 = na0; a1 = na1; a2 = na2; a3 = na3;
        b0 = n0;  b1 = n1;  b2 = n2;
    }

    // epilogue: D layout col=lane&15 (pos=w), row=(lane>>4)*4+ri (oc)
    int t = t0 + tzw;
    int wv = w0 + ln;
    if (wv < W_) {
        #pragma unroll
        for (int mt = 0; mt < 4; ++mt) {
            size_t obase = ((size_t)(b*64 + mt*16 + kg*4) * T_ + t) * HW_;
            #pragma unroll
            for (int j = 0; j < 3; ++j) {
                int hh = h0 + hw + j;
                if (hh < H_) {
                    float* o = out + obase + hh*W_ + wv;
                    #pragma unroll
                    for (int ri = 0; ri < 4; ++ri)
                        o[(size_t)ri * THW_] = acc[mt][j][ri];
                }
            }
        }
    }
}

extern "C" void kernel_launch(void* const* d_in, const int* in_sizes, int n_in,
                              void* d_out, int out_size, void* d_ws, size_t ws_size,
                              hipStream_t stream) {
    const float* x        = (const float*)d_in[0];
    const float* w_reduce = (const float*)d_in[1];
    const float* b_reduce = (const float*)d_in[2];
    const float* w_fc1    = (const float*)d_in[3];
    const float* b_fc1    = (const float*)d_in[4];
    const float* w_fc2    = (const float*)d_in[5];
    float* out = (float*)d_out;

    // ws layout: gap 4KB | h 8KB | wdyn 3.375MB | zblk 256B | xt 186.5MB (+slack)
    float* gap  = (float*)d_ws;
    float* h    = gap + 1024;
    short* wdyn = (short*)(h + 2048);
    short* zblk = wdyn + (size_t)B_*27*4096;
    short* xt   = zblk + 128;

    hipMemsetAsync(gap, 0, 1024*sizeof(float), stream);   // atomic accumulator
    transpose_kernel<<<B_*T_*HP_, 256, 0, stream>>>(x, xt, gap);
    fc_kernel       <<<1,         256, 0, stream>>>(gap, w_reduce, b_reduce, w_fc1, b_fc1, h);
    wdyn_kernel     <<<B_*27,     256, 0, stream>>>(w_fc2, h, wdyn, zblk);
    conv_kernel     <<<B_*495,    256, 0, stream>>>(xt, wdyn, zblk, out);
}

// Round 20
// 552.984 us; speedup vs baseline: 1.0464x; 1.0464x over previous
//
#include <hip/hip_runtime.h>
#include <hip/hip_bf16.h>
#include <stdint.h>

#define B_ 16
#define T_ 30
#define H_ 64
#define W_ 44
#define HW_ (H_*W_)            // 2816
#define THW_ (T_*HW_)          // 84480

// padded transposed layout: xt[b][half][t:30][hp:66][wp:46][32 ic] bf16
#define HP_ 66
#define WP_ 46
#define PPLANE_ (HP_*WP_)      // 3036
#define PPOS_ (T_*PPLANE_)     // 91080 pos per (b,half)

// conv tiling: 256 thr (4 waves), out tile 2t x 8h x 16w = 256 pos, 64 oc
#define NS2 720                // 4z x 10y x 18x staged rows (64 B each per K-half)

// LDS 16B-chunk swizzle (validated R3/R10: SQ_LDS_BANK_CONFLICT = 0)
#define SWZ(v) (((v) >> 1) & 3)

typedef __bf16 bf16x8 __attribute__((ext_vector_type(8)));
typedef float f32x4 __attribute__((ext_vector_type(4)));

static __device__ __forceinline__ short f2bf(float f) {
    __hip_bfloat16 h = __float2bfloat16(f);
    union { __hip_bfloat16 b; short s; } u; u.b = h; return u.s;
}

static __device__ __forceinline__ void gload_lds16(const short* g, short* l) {
    __builtin_amdgcn_global_load_lds((const __attribute__((address_space(1))) void*)g,
                                     (__attribute__((address_space(3))) void*)l, 16, 0, 0);
}

// ---------------- kernel 0: transpose + fused GAP ----------------
__global__ __launch_bounds__(256) void transpose_kernel(const float* __restrict__ x,
                                                        short* __restrict__ xt,
                                                        float* __restrict__ gap) {
    __shared__ short lb[64*52];
    __shared__ float gsum[64];
    int blk = blockIdx.x;
    int b = blk / (T_*HP_);
    int r = blk - b*(T_*HP_);
    int t = r / HP_;
    int hp = r - t*HP_;
    int tid = threadIdx.x;
    bool interior = (hp >= 1) && (hp <= H_);
    float rsum = 0.f;
    {
        int ic = tid >> 2, g = tid & 3;
        if (interior) {
            int h = hp - 1;
            const float4* row = (const float4*)(x + ((size_t)(b*64 + ic)*T_ + t)*HW_ + h*W_);
            #pragma unroll
            for (int q = g; q < 11; q += 4) {
                float4 v = row[q];
                short4 s4;
                s4.x = f2bf(v.x); s4.y = f2bf(v.y); s4.z = f2bf(v.z); s4.w = f2bf(v.w);
                *(short4*)&lb[ic*52 + q*4] = s4;
                rsum += (v.x + v.y) + (v.z + v.w);
            }
        }
        rsum += __shfl_xor(rsum, 1);
        rsum += __shfl_xor(rsum, 2);
        if ((tid & 3) == 0) gsum[ic] = rsum;
    }
    __syncthreads();
    if (interior && tid < 64)
        atomicAdd(&gap[b*64 + tid], gsum[tid] * (1.0f / THW_));
    for (int e = tid; e < WP_*16; e += 256) {
        int wp = e >> 4, i4 = (e & 15) * 4;
        short4 s4 = make_short4(0,0,0,0);
        if (interior && wp >= 1 && wp <= W_) {
            int w = wp - 1;
            s4.x = lb[(i4+0)*52 + w];
            s4.y = lb[(i4+1)*52 + w];
            s4.z = lb[(i4+2)*52 + w];
            s4.w = lb[(i4+3)*52 + w];
        }
        size_t pos = (size_t)t*PPLANE_ + hp*WP_ + wp;
        short* dst = xt + ((size_t)(b*2 + (i4 >> 5))*PPOS_ + pos)*32 + (i4 & 31);
        *(short4*)dst = s4;
    }
}

// ---------------- kernel 2: reduce FC + fc1 + sigmoid ----------------
__global__ __launch_bounds__(256) void fc_kernel(const float* __restrict__ gap,
        const float* __restrict__ w_reduce, const float* __restrict__ b_reduce,
        const float* __restrict__ w_fc1, const float* __restrict__ b_fc1,
        float* __restrict__ h_out) {
    __shared__ float gl[256];
    int t = threadIdx.x;
    {
        int b = t >> 4, j = t & 15;
        float a = b_reduce[j];
        #pragma unroll
        for (int c = 0; c < 64; ++c) a += gap[b*64 + c] * w_reduce[j*64 + c];
        gl[b*16 + j] = a;
    }
    __syncthreads();
    for (int idx = t; idx < 2048; idx += 256) {
        int b = idx >> 7, j = idx & 127;
        float v = b_fc1[j];
        #pragma unroll
        for (int i = 0; i < 16; ++i) v += gl[b*16 + i] * w_fc1[j*16 + i];
        h_out[idx] = 1.0f / (1.0f + expf(-v));
    }
}

// ---------------- kernel 3: dynamic weights bf16 (+ zero block) ----------------
__global__ __launch_bounds__(256) void wdyn_kernel(const float* __restrict__ w_fc2,
        const float* __restrict__ h, short* __restrict__ wdyn, short* __restrict__ zblk) {
    if (blockIdx.x == 0 && threadIdx.x < 128) zblk[threadIdx.x] = 0;
    int b = blockIdx.x / 27, tap = blockIdx.x % 27;
    short* dst = wdyn + ((size_t)b*27 + tap) * 4096;
    for (int e = threadIdx.x; e < 4096; e += 256) {
        int oc = e >> 6, ic = e & 63;
        float wv = w_fc2[(oc*64 + ic)*27 + tap];
        float hv = h[b*128 + 2*oc + (ic >> 5)];
        dst[e] = f2bf(wv * hv);
    }
}

#define DO_STEP(tap, r0, r1, r2, r3) do {                              \
    int _kd = (tap)/9, _rr = (tap)-_kd*9, _kh = _rr/3, _kw = _rr-_kh*3;\
    int _sb = (tzw + _kd)*180 + (hw4 + _kh)*18 + _kw + ln;             \
    _Pragma("unroll")                                                  \
    for (int _j = 0; _j < 4; ++_j) {                                   \
        int _s = _sb + _j*18;                                          \
        bf16x8 _bv = *(const bf16x8*)&xs[_s*32 + ((kg ^ SWZ(_s)) * 8)];\
        acc[0][_j] = __builtin_amdgcn_mfma_f32_16x16x32_bf16(r0, _bv, acc[0][_j], 0, 0, 0); \
        acc[1][_j] = __builtin_amdgcn_mfma_f32_16x16x32_bf16(r1, _bv, acc[1][_j], 0, 0, 0); \
        acc[2][_j] = __builtin_amdgcn_mfma_f32_16x16x32_bf16(r2, _bv, acc[2][_j], 0, 0, 0); \
        acc[3][_j] = __builtin_amdgcn_mfma_f32_16x16x32_bf16(r3, _bv, acc[3][_j], 0, 0, 0); \
    }                                                                  \
} while (0)

// ---------------- kernel 4: implicit-GEMM dynamic conv3d ----------------
// R12 champion structure (3 blocks/CU, acc[4][4], 2-barrier step) with two
// minimal deltas: (1) no s_setprio (m190: neutral-to-negative on lockstep
// structures — can starve sibling waves' LDS reads on the critical path);
// (2) barrier B is lgkmcnt-only (vmcnt provably 0 there: barrier A drained
// it and nothing vmem issues between).
__global__ __launch_bounds__(256, 3) void conv_kernel(const short* __restrict__ xt,
        const short* __restrict__ wdyn, const short* __restrict__ zblk,
        float* __restrict__ out) {
    __shared__ short xs[NS2*32];     // 46,080 B
    __shared__ short wb[2048];       //  4,096 B (one tap, one K-half)

    // XCD swizzle: 5760 blocks = 8 XCDs x 720 contiguous (5760 % 8 == 0)
    int bid = (blockIdx.x & 7) * 720 + (blockIdx.x >> 3);
    int b = bid / 360; int r = bid - b*360;
    int tzt = r / 24; r -= tzt*24;
    int tyt = r / 3;  int txt = r - tyt*3;
    int t0 = tzt*2, h0 = tyt*8, w0 = txt*16;

    int tid = threadIdx.x, wid = tid >> 6, lane = tid & 63;
    int ln = lane & 15, kg = lane >> 4;
    int l4 = lane >> 2, c = lane & 3;
    int tzw = wid & 1, hw4 = (wid >> 1) * 4;
    int woc = tid >> 2, wseg = tid & 3;          // weight staging role

    const short* wdb = wdyn + (size_t)b * 27 * 4096;

    f32x4 acc[4][4];
    #pragma unroll
    for (int mt = 0; mt < 4; ++mt)
        #pragma unroll
        for (int j = 0; j < 4; ++j) acc[mt][j] = f32x4{0.f, 0.f, 0.f, 0.f};

    auto stage_x = [&](int half) {               // 45 gload_lds over 4 waves
        const short* xbh = xt + (size_t)(b*2 + half) * PPOS_ * 32;
        #pragma unroll
        for (int ii = 0; ii < 12; ++ii) {
            int inst = ii*4 + wid;
            if (inst < 45) {
                int s = inst*16 + l4;
                int z = s / 180; int rr = s - z*180;
                int y = rr / 18; int xx = rr - y*18;
                int t = t0 + z - 1;
                int seg = (c ^ SWZ(s)) * 8;
                const short* src = ((unsigned)t < (unsigned)T_)
                    ? xbh + ((size_t)t*PPLANE_ + (h0+y)*WP_ + (w0+xx))*32 + seg
                    : zblk + seg;
                gload_lds16(src, xs + inst*512);
            }
        }
    };

    // prologue: stage xs half 0, prefetch tap-0 weights into a register
    stage_x(0);
    uint4 wr = *(const uint4*)(wdb + woc*64 + wseg*8);
    short* wdst = wb + woc*32 + ((wseg ^ SWZ(woc)) * 8);

    for (int g = 0; g < 54; ++g) {
        __syncthreads();                         // (A) wb reads of step g-1 done;
                                                 //     drains wr(g) (full drain OK)
        *(uint4*)wdst = wr;                      // publish tap g weights
        asm volatile("s_waitcnt lgkmcnt(0)" ::: "memory");
        __builtin_amdgcn_s_barrier();            // (B) wb visible; lgkm-only
        if (g < 53) {                            // prefetch tap g+1 (inside MFMA
            int gn = g + 1;                      //  phase for max latency cover)
            int nt = gn - ((gn >= 27) ? 27 : 0);
            int nh = (gn >= 27) ? 32 : 0;
            wr = *(const uint4*)(wdb + nt*4096 + nh + woc*64 + wseg*8);
        }
        bf16x8 a0, a1, a2, a3;
        {
            int cw = (kg ^ SWZ(ln)) * 8;
            a0 = *(const bf16x8*)&wb[(ln     )*32 + cw];
            a1 = *(const bf16x8*)&wb[(ln + 16)*32 + cw];
            a2 = *(const bf16x8*)&wb[(ln + 32)*32 + cw];
            a3 = *(const bf16x8*)&wb[(ln + 48)*32 + cw];
        }
        int tap = g - ((g >= 27) ? 27 : 0);
        DO_STEP(tap, a0, a1, a2, a3);
        if (g == 26) {                           // half transition
            __syncthreads();                     // xs(0) reads complete
            stage_x(1);                          // drained by next sync (A)
        }
    }

    // epilogue: D layout col=lane&15 (pos=w), row=(lane>>4)*4+ri (oc)
    int t = t0 + tzw;
    int wv = w0 + ln;
    if (wv < W_) {
        #pragma unroll
        for (int mt = 0; mt < 4; ++mt) {
            size_t obase = ((size_t)(b*64 + mt*16 + kg*4) * T_ + t) * HW_;
            #pragma unroll
            for (int j = 0; j < 4; ++j) {
                float* o = out + obase + (h0 + hw4 + j)*W_ + wv;
                #pragma unroll
                for (int ri = 0; ri < 4; ++ri)
                    o[(size_t)ri * THW_] = acc[mt][j][ri];
            }
        }
    }
}

extern "C" void kernel_launch(void* const* d_in, const int* in_sizes, int n_in,
                              void* d_out, int out_size, void* d_ws, size_t ws_size,
                              hipStream_t stream) {
    const float* x        = (const float*)d_in[0];
    const float* w_reduce = (const float*)d_in[1];
    const float* b_reduce = (const float*)d_in[2];
    const float* w_fc1    = (const float*)d_in[3];
    const float* b_fc1    = (const float*)d_in[4];
    const float* w_fc2    = (const float*)d_in[5];
    float* out = (float*)d_out;

    // ws layout: gap 4KB | h 8KB | wdyn 3.375MB | zblk 256B | xt 186.5MB (+slack)
    float* gap  = (float*)d_ws;
    float* h    = gap + 1024;
    short* wdyn = (short*)(h + 2048);
    short* zblk = wdyn + (size_t)B_*27*4096;
    short* xt   = zblk + 128;

    hipMemsetAsync(gap, 0, 1024*sizeof(float), stream);   // atomic accumulator
    transpose_kernel<<<B_*T_*HP_, 256, 0, stream>>>(x, xt, gap);
    fc_kernel       <<<1,         256, 0, stream>>>(gap, w_reduce, b_reduce, w_fc1, b_fc1, h);
    wdyn_kernel     <<<B_*27,     256, 0, stream>>>(w_fc2, h, wdyn, zblk);
    conv_kernel     <<<B_*360,    256, 0, stream>>>(xt, wdyn, zblk, out);
}

// Round 21
// 534.273 us; speedup vs baseline: 1.0830x; 1.0350x over previous
//
#include <hip/hip_runtime.h>
#include <hip/hip_bf16.h>
#include <stdint.h>

#define B_ 16
#define T_ 30
#define H_ 64
#define W_ 44
#define HW_ (H_*W_)            // 2816
#define THW_ (T_*HW_)          // 84480

// padded transposed layout: xt[b][half][t:30][hp:66][wp:46][32 ic] bf16
#define HP_ 66
#define WP_ 46
#define PPLANE_ (HP_*WP_)      // 3036
#define PPOS_ (T_*PPLANE_)     // 91080 pos per (b,half)

// conv tiling: 256 thr (4 waves), out tile 2t x 8h x 16w = 256 pos, 64 oc
#define NS2 720                // 4z x 10y x 18x staged rows (64 B each per K-half)

// LDS 16B-chunk swizzle (validated R3/R10: SQ_LDS_BANK_CONFLICT = 0)
#define SWZ(v) (((v) >> 1) & 3)

typedef __bf16 bf16x8 __attribute__((ext_vector_type(8)));
typedef float f32x4 __attribute__((ext_vector_type(4)));
typedef short short8 __attribute__((ext_vector_type(8)));

static __device__ __forceinline__ short f2bf(float f) {
    __hip_bfloat16 h = __float2bfloat16(f);
    union { __hip_bfloat16 b; short s; } u; u.b = h; return u.s;
}

static __device__ __forceinline__ void gload_lds16(const short* g, short* l) {
    __builtin_amdgcn_global_load_lds((const __attribute__((address_space(1))) void*)g,
                                     (__attribute__((address_space(3))) void*)l, 16, 0, 0);
}

// ---------------- kernel 0: transpose + fused GAP ----------------
// write loop v2: wave writes 16 contiguous pos x 64 B = 1 KB per half
// (short8 = 16 B/lane), instead of 8 B/lane split across halves.
__global__ __launch_bounds__(256) void transpose_kernel(const float* __restrict__ x,
                                                        short* __restrict__ xt,
                                                        float* __restrict__ gap) {
    __shared__ short lb[64*52];
    __shared__ float gsum[64];
    int blk = blockIdx.x;
    int b = blk / (T_*HP_);
    int r = blk - b*(T_*HP_);
    int t = r / HP_;
    int hp = r - t*HP_;
    int tid = threadIdx.x;
    bool interior = (hp >= 1) && (hp <= H_);
    float rsum = 0.f;
    {
        int ic = tid >> 2, g = tid & 3;
        if (interior) {
            int h = hp - 1;
            const float4* row = (const float4*)(x + ((size_t)(b*64 + ic)*T_ + t)*HW_ + h*W_);
            #pragma unroll
            for (int q = g; q < 11; q += 4) {
                float4 v = row[q];
                short4 s4;
                s4.x = f2bf(v.x); s4.y = f2bf(v.y); s4.z = f2bf(v.z); s4.w = f2bf(v.w);
                *(short4*)&lb[ic*52 + q*4] = s4;
                rsum += (v.x + v.y) + (v.z + v.w);
            }
        }
        rsum += __shfl_xor(rsum, 1);
        rsum += __shfl_xor(rsum, 2);
        if ((tid & 3) == 0) gsum[ic] = rsum;
    }
    __syncthreads();
    if (interior && tid < 64)
        atomicAdd(&gap[b*64 + tid], gsum[tid] * (1.0f / THW_));
    // 368 units: 2 halves x 46 wp x 4 chunks of 16 B. Lanes 0..63 of a wave
    // cover half 0, wp 0..15 -> 1 KB contiguous store.
    for (int e = tid; e < 368; e += 256) {
        int half = e / 184;
        int rr = e - half*184;
        int wp = rr >> 2, chunk = rr & 3;
        int ic0 = half*32 + chunk*8;
        short8 v;
        #pragma unroll
        for (int j = 0; j < 8; ++j) v[j] = 0;
        if (interior && wp >= 1 && wp <= W_) {
            int w = wp - 1;
            #pragma unroll
            for (int j = 0; j < 8; ++j) v[j] = lb[(ic0 + j)*52 + w];
        }
        size_t pos = (size_t)t*PPLANE_ + hp*WP_ + wp;
        short* dst = xt + ((size_t)(b*2 + half)*PPOS_ + pos)*32 + chunk*8;
        *(short8*)dst = v;
    }
}

// ---------------- kernel 2: reduce FC + fc1 + sigmoid ----------------
__global__ __launch_bounds__(256) void fc_kernel(const float* __restrict__ gap,
        const float* __restrict__ w_reduce, const float* __restrict__ b_reduce,
        const float* __restrict__ w_fc1, const float* __restrict__ b_fc1,
        float* __restrict__ h_out) {
    __shared__ float gl[256];
    int t = threadIdx.x;
    {
        int b = t >> 4, j = t & 15;
        float a = b_reduce[j];
        #pragma unroll
        for (int c = 0; c < 64; ++c) a += gap[b*64 + c] * w_reduce[j*64 + c];
        gl[b*16 + j] = a;
    }
    __syncthreads();
    for (int idx = t; idx < 2048; idx += 256) {
        int b = idx >> 7, j = idx & 127;
        float v = b_fc1[j];
        #pragma unroll
        for (int i = 0; i < 16; ++i) v += gl[b*16 + i] * w_fc1[j*16 + i];
        h_out[idx] = 1.0f / (1.0f + expf(-v));
    }
}

// ---------------- kernel 3: dynamic weights bf16 (+ zero block) ----------------
__global__ __launch_bounds__(256) void wdyn_kernel(const float* __restrict__ w_fc2,
        const float* __restrict__ h, short* __restrict__ wdyn, short* __restrict__ zblk) {
    if (blockIdx.x == 0 && threadIdx.x < 128) zblk[threadIdx.x] = 0;
    int b = blockIdx.x / 27, tap = blockIdx.x % 27;
    short* dst = wdyn + ((size_t)b*27 + tap) * 4096;
    for (int e = threadIdx.x; e < 4096; e += 256) {
        int oc = e >> 6, ic = e & 63;
        float wv = w_fc2[(oc*64 + ic)*27 + tap];
        float hv = h[b*128 + 2*oc + (ic >> 5)];
        dst[e] = f2bf(wv * hv);
    }
}

#define DO_STEP(tap, r0, r1, r2, r3) do {                              \
    int _kd = (tap)/9, _rr = (tap)-_kd*9, _kh = _rr/3, _kw = _rr-_kh*3;\
    int _sb = (tzw + _kd)*180 + (hw4 + _kh)*18 + _kw + ln;             \
    __builtin_amdgcn_s_setprio(1);                                     \
    _Pragma("unroll")                                                  \
    for (int _j = 0; _j < 4; ++_j) {                                   \
        int _s = _sb + _j*18;                                          \
        bf16x8 _bv = *(const bf16x8*)&xs[_s*32 + ((kg ^ SWZ(_s)) * 8)];\
        acc[0][_j] = __builtin_amdgcn_mfma_f32_16x16x32_bf16(r0, _bv, acc[0][_j], 0, 0, 0); \
        acc[1][_j] = __builtin_amdgcn_mfma_f32_16x16x32_bf16(r1, _bv, acc[1][_j], 0, 0, 0); \
        acc[2][_j] = __builtin_amdgcn_mfma_f32_16x16x32_bf16(r2, _bv, acc[2][_j], 0, 0, 0); \
        acc[3][_j] = __builtin_amdgcn_mfma_f32_16x16x32_bf16(r3, _bv, acc[3][_j], 0, 0, 0); \
    }                                                                  \
    __builtin_amdgcn_s_setprio(0);                                     \
} while (0)

// ---------------- kernel 4: implicit-GEMM dynamic conv3d ----------------
// R12 champion restored VERBATIM (3 blocks/CU, acc[4][4], 2-barrier step,
// setprio on). R19's deltas (no setprio, lgkm-only barrier B) regressed -8%.
__global__ __launch_bounds__(256, 3) void conv_kernel(const short* __restrict__ xt,
        const short* __restrict__ wdyn, const short* __restrict__ zblk,
        float* __restrict__ out) {
    __shared__ short xs[NS2*32];     // 46,080 B
    __shared__ short wb[2048];       //  4,096 B (one tap, one K-half)

    // XCD swizzle: 5760 blocks = 8 XCDs x 720 contiguous (5760 % 8 == 0)
    int bid = (blockIdx.x & 7) * 720 + (blockIdx.x >> 3);
    int b = bid / 360; int r = bid - b*360;
    int tzt = r / 24; r -= tzt*24;
    int tyt = r / 3;  int txt = r - tyt*3;
    int t0 = tzt*2, h0 = tyt*8, w0 = txt*16;

    int tid = threadIdx.x, wid = tid >> 6, lane = tid & 63;
    int ln = lane & 15, kg = lane >> 4;
    int l4 = lane >> 2, c = lane & 3;
    int tzw = wid & 1, hw4 = (wid >> 1) * 4;
    int woc = tid >> 2, wseg = tid & 3;          // weight staging role

    const short* wdb = wdyn + (size_t)b * 27 * 4096;

    f32x4 acc[4][4];
    #pragma unroll
    for (int mt = 0; mt < 4; ++mt)
        #pragma unroll
        for (int j = 0; j < 4; ++j) acc[mt][j] = f32x4{0.f, 0.f, 0.f, 0.f};

    auto stage_x = [&](int half) {               // 45 gload_lds over 4 waves
        const short* xbh = xt + (size_t)(b*2 + half) * PPOS_ * 32;
        #pragma unroll
        for (int ii = 0; ii < 12; ++ii) {
            int inst = ii*4 + wid;
            if (inst < 45) {
                int s = inst*16 + l4;
                int z = s / 180; int rr = s - z*180;
                int y = rr / 18; int xx = rr - y*18;
                int t = t0 + z - 1;
                int seg = (c ^ SWZ(s)) * 8;
                const short* src = ((unsigned)t < (unsigned)T_)
                    ? xbh + ((size_t)t*PPLANE_ + (h0+y)*WP_ + (w0+xx))*32 + seg
                    : zblk + seg;
                gload_lds16(src, xs + inst*512);
            }
        }
    };

    // prologue: stage xs half 0, prefetch tap-0 weights into a register
    stage_x(0);
    uint4 wr = *(const uint4*)(wdb + woc*64 + wseg*8);
    short* wdst = wb + woc*32 + ((wseg ^ SWZ(woc)) * 8);

    for (int g = 0; g < 54; ++g) {
        __syncthreads();                         // (A) wb reads of step g-1 done
        *(uint4*)wdst = wr;                      // publish tap g weights
        __syncthreads();                         // (B) wb visible; vmcnt==0 -> free
        if (g < 53) {                            // prefetch tap g+1 (inside MFMA
            int gn = g + 1;                      //  phase for max latency cover)
            int nt = gn - ((gn >= 27) ? 27 : 0);
            int nh = (gn >= 27) ? 32 : 0;
            wr = *(const uint4*)(wdb + nt*4096 + nh + woc*64 + wseg*8);
        }
        bf16x8 a0, a1, a2, a3;
        {
            int cw = (kg ^ SWZ(ln)) * 8;
            a0 = *(const bf16x8*)&wb[(ln     )*32 + cw];
            a1 = *(const bf16x8*)&wb[(ln + 16)*32 + cw];
            a2 = *(const bf16x8*)&wb[(ln + 32)*32 + cw];
            a3 = *(const bf16x8*)&wb[(ln + 48)*32 + cw];
        }
        int tap = g - ((g >= 27) ? 27 : 0);
        DO_STEP(tap, a0, a1, a2, a3);
        if (g == 26) {                           // half transition
            __syncthreads();                     // xs(0) reads complete
            stage_x(1);                          // drained by next sync (A)
        }
    }

    // epilogue: D layout col=lane&15 (pos=w), row=(lane>>4)*4+ri (oc)
    int t = t0 + tzw;
    int wv = w0 + ln;
    if (wv < W_) {
        #pragma unroll
        for (int mt = 0; mt < 4; ++mt) {
            size_t obase = ((size_t)(b*64 + mt*16 + kg*4) * T_ + t) * HW_;
            #pragma unroll
            for (int j = 0; j < 4; ++j) {
                float* o = out + obase + (h0 + hw4 + j)*W_ + wv;
                #pragma unroll
                for (int ri = 0; ri < 4; ++ri)
                    o[(size_t)ri * THW_] = acc[mt][j][ri];
            }
        }
    }
}

extern "C" void kernel_launch(void* const* d_in, const int* in_sizes, int n_in,
                              void* d_out, int out_size, void* d_ws, size_t ws_size,
                              hipStream_t stream) {
    const float* x        = (const float*)d_in[0];
    const float* w_reduce = (const float*)d_in[1];
    const float* b_reduce = (const float*)d_in[2];
    const float* w_fc1    = (const float*)d_in[3];
    const float* b_fc1    = (const float*)d_in[4];
    const float* w_fc2    = (const float*)d_in[5];
    float* out = (float*)d_out;

    // ws layout: gap 4KB | h 8KB | wdyn 3.375MB | zblk 256B | xt 186.5MB (+slack)
    float* gap  = (float*)d_ws;
    float* h    = gap + 1024;
    short* wdyn = (short*)(h + 2048);
    short* zblk = wdyn + (size_t)B_*27*4096;
    short* xt   = zblk + 128;

    hipMemsetAsync(gap, 0, 1024*sizeof(float), stream);   // atomic accumulator
    transpose_kernel<<<B_*T_*HP_, 256, 0, stream>>>(x, xt, gap);
    fc_kernel       <<<1,         256, 0, stream>>>(gap, w_reduce, b_reduce, w_fc1, b_fc1, h);
    wdyn_kernel     <<<B_*27,     256, 0, stream>>>(w_fc2, h, wdyn, zblk);
    conv_kernel     <<<B_*360,    256, 0, stream>>>(xt, wdyn, zblk, out);
}